// Round 3
// baseline (362.332 us; speedup 1.0000x reference)
//
#include <hip/hip_runtime.h>
#include <math.h>

#define NS   2048
#define TL   81
#define NBN  15
#define DA   48
#define SQL  31
#define KD   1488   // SEQ*D_ATT
#define DL   256
#define MID  40

#define INV_SQRT_BN 0.99999500003749969f   // 1/sqrt(1+1e-5)
#define SCALE_ATT   0.35355339059327373f   // 1/sqrt(8)

// ---------------- Kernel 1 v3: lane=s, 2 samples/wave, scalar-operand weights ----------------
// Block = 64 threads (1 wave). Lanes 0..31: sample 2*bx, lanes 32..63: sample 2*bx+1.
// All weight reads are wave-uniform -> s_load; h/y/o in VGPRs; only K,V through LDS.
__global__ __launch_bounds__(64)
void attn_kernel(const float* __restrict__ x5, const float* __restrict__ noise,
                 const float* __restrict__ enc_w, const float* __restrict__ enc_b,
                 const float* __restrict__ enc_g, const float* __restrict__ enc_bb,
                 const float* __restrict__ ln_a, const float* __restrict__ ln_b,
                 const float* __restrict__ wq, const float* __restrict__ bq,
                 const float* __restrict__ wk, const float* __restrict__ bk,
                 const float* __restrict__ wv, const float* __restrict__ bv,
                 const float* __restrict__ wo, const float* __restrict__ bo,
                 float* __restrict__ y2)
{
    __shared__ __align__(16) float sK[2*32*12];   // [smp][s][12] (8 used, stride 12 for 16B align)
    __shared__ __align__(16) float sV[2*32*12];

    const int lane = threadIdx.x;
    const int smp  = lane >> 5;
    const int s    = lane & 31;
    const int scl  = (s < 31) ? s : 30;           // lane 31 is dummy; clamp loads
    const int n    = blockIdx.x*2 + smp;

    // ---- per-lane 3-vector input (root-subtracted mid-frame | noise) ----
    float x0, x1, x2;
    if (scl < 16){
        const float* base = x5 + ((size_t)n*TL + MID)*48;
        x0 = base[scl*3+0] - base[0];
        x1 = base[scl*3+1] - base[1];
        x2 = base[scl*3+2] - base[2];
    } else {
        const float* nb = noise + (size_t)n*45 + (scl*3 - 48);
        x0 = nb[0]; x1 = nb[1]; x2 = nb[2];
    }

    // ---- encoder + BN + relu (enc params uniform -> SGPR) ----
    float y[48];
    #pragma unroll
    for (int f=0; f<48; f++){
        float a = enc_b[f] + x0*enc_w[f*3+0] + x1*enc_w[f*3+1] + x2*enc_w[f*3+2];
        float v = a*(enc_g[f]*INV_SQRT_BN) + enc_bb[f];
        y[f] = fmaxf(v, 0.0f);
    }

    // ---- layer norm (lane-local; divisor 47, eps on std) ----
    float mean = 0.f;
    #pragma unroll
    for (int f=0; f<48; f++) mean += y[f];
    mean *= (1.0f/48.0f);
    float vs = 0.f;
    #pragma unroll
    for (int f=0; f<48; f++){ float d = y[f]-mean; vs += d*d; }
    const float rstd = 1.0f/(sqrtf(vs*(1.0f/47.0f)) + 1e-6f);
    float h[48];
    #pragma unroll
    for (int f=0; f<48; f++) h[f] = ln_a[f]*(y[f]-mean)*rstd + ln_b[f];

    // ---- per-head: QKV chunk -> LDS(K,V) -> attention -> fold into o via wo ----
    float o[48];
    #pragma unroll
    for (int f=0; f<48; f++) o[f] = 0.f;

    #pragma unroll 1
    for (int hd=0; hd<6; hd++){
        const float* wqh = wq + hd*8*48;
        const float* wkh = wk + hd*8*48;
        const float* wvh = wv + hd*8*48;
        float q8[8], k8[8], v8[8];
        #pragma unroll
        for (int j=0; j<8; j++){
            q8[j] = bq[hd*8+j]; k8[j] = bk[hd*8+j]; v8[j] = bv[hd*8+j];
        }
        // 3 interleaved dependent chains per j -> issue-bound; weights contiguous per (mat,j)
        #pragma unroll
        for (int j=0; j<8; j++){
            const float* wqr = wqh + j*48;
            const float* wkr = wkh + j*48;
            const float* wvr = wvh + j*48;
            float aq = q8[j], ak = k8[j], av = v8[j];
            #pragma unroll
            for (int c=0; c<48; c++){
                float hc = h[c];
                aq += hc*wqr[c];
                ak += hc*wkr[c];
                av += hc*wvr[c];
            }
            q8[j] = aq; k8[j] = ak; v8[j] = av;
        }

        // stage K,V (own row; stride 12 floats)
        float* kr = sK + (smp*32+s)*12;
        float* vr = sV + (smp*32+s)*12;
        float4 t0, t1;
        t0.x=k8[0]; t0.y=k8[1]; t0.z=k8[2]; t0.w=k8[3];
        t1.x=k8[4]; t1.y=k8[5]; t1.z=k8[6]; t1.w=k8[7];
        *(float4*)(kr) = t0; *(float4*)(kr+4) = t1;
        t0.x=v8[0]; t0.y=v8[1]; t0.z=v8[2]; t0.w=v8[3];
        t1.x=v8[4]; t1.y=v8[5]; t1.z=v8[6]; t1.w=v8[7];
        *(float4*)(vr) = t0; *(float4*)(vr+4) = t1;
        __syncthreads();

        // scores (broadcast reads: all lanes of a half read the same row)
        float sc[31];
        float mx = -1e30f;
        #pragma unroll
        for (int ki=0; ki<31; ki++){
            const float* kp = sK + (smp*32+ki)*12;
            float4 ka = *(const float4*)(kp);
            float4 kb = *(const float4*)(kp+4);
            float d = q8[0]*ka.x + q8[1]*ka.y + q8[2]*ka.z + q8[3]*ka.w
                    + q8[4]*kb.x + q8[5]*kb.y + q8[6]*kb.z + q8[7]*kb.w;
            d *= SCALE_ATT;
            sc[ki] = d;
            mx = fmaxf(mx, d);
        }
        float ssum = 0.f;
        #pragma unroll
        for (int ki=0; ki<31; ki++){
            float e = __expf(sc[ki]-mx);
            sc[ki] = e; ssum += e;
        }
        const float rin = 1.0f/ssum;

        float c8[8];
        #pragma unroll
        for (int j=0; j<8; j++) c8[j] = 0.f;
        #pragma unroll
        for (int ki=0; ki<31; ki++){
            const float* vp = sV + (smp*32+ki)*12;
            float4 va = *(const float4*)(vp);
            float4 vb = *(const float4*)(vp+4);
            float p = sc[ki];
            c8[0] += p*va.x; c8[1] += p*va.y; c8[2] += p*va.z; c8[3] += p*va.w;
            c8[4] += p*vb.x; c8[5] += p*vb.y; c8[6] += p*vb.z; c8[7] += p*vb.w;
        }
        #pragma unroll
        for (int j=0; j<8; j++) c8[j] *= rin;

        // fold this head's ctx into o via wo columns (uniform -> SGPR)
        #pragma unroll
        for (int f=0; f<48; f++){
            const float* wor = wo + f*48 + hd*8;
            float a = o[f];
            #pragma unroll
            for (int j=0; j<8; j++) a += c8[j]*wor[j];
            o[f] = a;
        }
        __syncthreads();   // protect sK/sV before next head overwrites
    }

    // ---- residual + bias -> y2 (lane writes its contiguous 48 floats) ----
    if (s < 31){
        float* dst = y2 + (size_t)n*KD + s*48;
        #pragma unroll
        for (int f4=0; f4<12; f4++){
            float4 v;
            v.x = y[f4*4+0] + o[f4*4+0] + bo[f4*4+0];
            v.y = y[f4*4+1] + o[f4*4+1] + bo[f4*4+1];
            v.z = y[f4*4+2] + o[f4*4+2] + bo[f4*4+2];
            v.w = y[f4*4+3] + o[f4*4+3] + bo[f4*4+3];
            *(float4*)(dst + f4*4) = v;
        }
    }
}

// ---------------- Kernel 2: raw dot C = y2 @ w1^T, K-split 6, partials -> d_out scratch ----------------
#define KSP 6
#define KPS 248     // 1488/6
#define KCH 8

__global__ __launch_bounds__(256)
void gemm1_kernel(const float* __restrict__ y2, const float* __restrict__ w1,
                  float* __restrict__ y3p)
{
    __shared__ __align__(16) float sB[KCH*256];     // [kk][n]  8KB
    __shared__ __align__(16) float sA[KCH*20];      // [kk][m]  640B
    const int tid = threadIdx.x;
    const int bx = blockIdx.x;                      // 768 blocks
    const int m0 = (bx & 127) * 16;
    const int split = bx >> 7;                      // 0..5
    const int ks0 = split * KPS;
    const int c0 = (tid & 15)*4 + (tid >> 6)*64;    // output cols c0..c0+3
    const int r0 = ((tid >> 4) & 3)*4;              // output rows r0..r0+3

    const int bn = tid >> 1;
    const int bg = (tid & 1)*4;
    const int ar = tid >> 1;
    const int ag = (tid & 1)*4;

    float acc[4][4];
    #pragma unroll
    for (int i=0;i<4;i++)
        #pragma unroll
        for (int j=0;j<4;j++) acc[i][j]=0.f;

    for (int ch=0; ch<31; ch++){
        const int k0 = ks0 + ch*KCH;
        float4 b0v = *(const float4*)(w1 + (size_t)bn*KD        + k0 + bg);
        float4 b1v = *(const float4*)(w1 + (size_t)(bn+128)*KD  + k0 + bg);
        float4 av;
        if (tid < 32) av = *(const float4*)(y2 + (size_t)(m0+ar)*KD + k0 + ag);
        __syncthreads();
        sB[(bg+0)*256 + bn] = b0v.x;  sB[(bg+1)*256 + bn] = b0v.y;
        sB[(bg+2)*256 + bn] = b0v.z;  sB[(bg+3)*256 + bn] = b0v.w;
        sB[(bg+0)*256 + bn+128] = b1v.x;  sB[(bg+1)*256 + bn+128] = b1v.y;
        sB[(bg+2)*256 + bn+128] = b1v.z;  sB[(bg+3)*256 + bn+128] = b1v.w;
        if (tid < 32){
            sA[(ag+0)*20 + ar] = av.x;  sA[(ag+1)*20 + ar] = av.y;
            sA[(ag+2)*20 + ar] = av.z;  sA[(ag+3)*20 + ar] = av.w;
        }
        __syncthreads();
        #pragma unroll
        for (int kk=0; kk<KCH; kk++){
            float4 b = *(const float4*)(sB + kk*256 + c0);
            float4 a = *(const float4*)(sA + kk*20 + r0);
            acc[0][0] += a.x*b.x; acc[0][1] += a.x*b.y; acc[0][2] += a.x*b.z; acc[0][3] += a.x*b.w;
            acc[1][0] += a.y*b.x; acc[1][1] += a.y*b.y; acc[1][2] += a.y*b.z; acc[1][3] += a.y*b.w;
            acc[2][0] += a.z*b.x; acc[2][1] += a.z*b.y; acc[2][2] += a.z*b.z; acc[2][3] += a.z*b.w;
            acc[3][0] += a.w*b.x; acc[3][1] += a.w*b.y; acc[3][2] += a.w*b.z; acc[3][3] += a.w*b.w;
        }
    }

    float* dst = y3p + (size_t)split*NS*DL;
    #pragma unroll
    for (int i=0;i<4;i++){
        float4 v; v.x=acc[i][0]; v.y=acc[i][1]; v.z=acc[i][2]; v.w=acc[i][3];
        *(float4*)(dst + (size_t)(m0+r0+i)*DL + c0) = v;
    }
}

// ---------------- Kernel 3: reduce splits + bias/BN/leaky; y4 = leaky(y3 @ w2^T + b2); axis/theta ----------------
__global__ __launch_bounds__(256)
void head_kernel(const float* __restrict__ y3p, const float* __restrict__ w2,
                 const float* __restrict__ b2, const float* __restrict__ b1,
                 const float* __restrict__ g1, const float* __restrict__ bb1,
                 float* __restrict__ at)
{
    __shared__ float swc[64*60];
    __shared__ __align__(16) float sy3[16*256];
    __shared__ float sy4[16*61];
    const int tid = threadIdx.x;
    const int n0 = blockIdx.x * 16;

    #pragma unroll
    for (int l=0;l<4;l++){
        int idx = tid + l*256;
        int s = idx >> 6, i4 = (idx & 63) << 2;
        const float* src = y3p + (size_t)(n0+s)*256 + i4;
        float4 v = *(const float4*)(src);
        #pragma unroll
        for (int sl=1; sl<6; sl++){
            float4 p = *(const float4*)(src + (size_t)sl*NS*DL);
            v.x += p.x; v.y += p.y; v.z += p.z; v.w += p.w;
        }
        const float4 vb = *(const float4*)(b1 + i4);
        const float4 vg = *(const float4*)(g1 + i4);
        const float4 vsb = *(const float4*)(bb1 + i4);
        v.x = (v.x + vb.x)*(vg.x*INV_SQRT_BN) + vsb.x;  v.x = v.x>=0.f? v.x : 0.01f*v.x;
        v.y = (v.y + vb.y)*(vg.y*INV_SQRT_BN) + vsb.y;  v.y = v.y>=0.f? v.y : 0.01f*v.y;
        v.z = (v.z + vb.z)*(vg.z*INV_SQRT_BN) + vsb.z;  v.z = v.z>=0.f? v.z : 0.01f*v.z;
        v.w = (v.w + vb.w)*(vg.w*INV_SQRT_BN) + vsb.w;  v.w = v.w>=0.f? v.w : 0.01f*v.w;
        *(float4*)(sy3 + s*256 + i4) = v;
    }

    float acc[4]; int ss[4], mm[4];
    #pragma unroll
    for (int l=0;l<4;l++){
        int uu = tid + l*256;
        ss[l]=0; mm[l]=0; acc[l]=0.f;
        if (uu < 960){ ss[l]=uu/60; mm[l]=uu-ss[l]*60; acc[l]=b2[mm[l]]; }
    }

    for (int ch=0; ch<4; ch++){
        const int i0 = ch*64;
        __syncthreads();
        #pragma unroll
        for (int l=0;l<15;l++){
            int idx = tid + l*256;
            int m = idx >> 6, io = idx & 63;
            swc[io*60 + m] = w2[(size_t)m*256 + i0 + io];
        }
        __syncthreads();
        #pragma unroll
        for (int l=0;l<4;l++){
            int uu = tid + l*256;
            if (uu < 960){
                const float* yy = sy3 + ss[l]*256 + i0;
                float a = acc[l];
                #pragma unroll 8
                for (int io=0; io<64; io++) a += yy[io]*swc[io*60 + mm[l]];
                acc[l] = a;
            }
        }
    }
    __syncthreads();
    #pragma unroll
    for (int l=0;l<4;l++){
        int uu = tid + l*256;
        if (uu < 960){
            float a = acc[l];
            sy4[ss[l]*61 + mm[l]] = a>=0.f? a : 0.01f*a;
        }
    }
    __syncthreads();
    if (tid < 240){
        int s = tid/15, b = tid - s*15;
        const float* y4 = sy4 + s*61 + b*4;
        float ax=y4[0], ay=y4[1], az=y4[2], th=y4[3];
        float nr = sqrtf(ax*ax+ay*ay+az*az);
        float4 o;
        o.x = ax/nr; o.y = ay/nr; o.z = az/nr; o.w = th/81.0f;
        *(float4*)(at + (size_t)(n0+s)*60 + b*4) = o;
    }
}

// ---------------- Kernel 4: per-(n,t) Rodrigues + FK + ba_diff ----------------
__global__ __launch_bounds__(256)
void pose_kernel(const float* __restrict__ x5, const float* __restrict__ at,
                 float* __restrict__ out)
{
    const int gid = blockIdx.x*256 + threadIdx.x;
    if (gid >= NS*TL) return;
    const int n = gid / TL;
    const int t = gid - n*TL;
    const float ft = (float)t;

    float4 pv[12];
    {
        const float4* src = (const float4*)(x5 + (size_t)gid*48);
        #pragma unroll
        for (int i=0;i<12;i++) pv[i] = src[i];
    }
    float* p = (float*)pv;
    const float4* ab = (const float4*)(at + (size_t)n*60);

    float4 posv[12];
    float* pos = (float*)posv;
    pos[0]=p[0]; pos[1]=p[1]; pos[2]=p[2];
    float ba[15];

    const int PJ[15] = {0,1,2,0,4,5,0,7,8,9,8,11,12,8,14};
    const int CJ[15] = {1,2,3,4,5,6,7,8,9,10,11,12,13,14,15};

    #pragma unroll
    for (int b=0;b<15;b++){
        const int pj = PJ[b], cj = CJ[b];
        float bx = p[cj*3+0]-p[pj*3+0];
        float by = p[cj*3+1]-p[pj*3+1];
        float bz = p[cj*3+2]-p[pj*3+2];
        float bl = sqrtf(bx*bx+by*by+bz*bz);
        float ux = bx/bl, uy = by/bl, uz = bz/bl;
        float mx, my, mz;
        if (b==6 || b==7){
            mx=ux; my=uy; mz=uz;
        } else {
            float4 a = ab[b];
            float ang = a.w * ft;
            float cs = cosf(ang), sn = sinf(ang);
            float kd = a.x*ux + a.y*uy + a.z*uz;
            float cx = a.y*uz - a.z*uy;
            float cy = a.z*ux - a.x*uz;
            float cz = a.x*uy - a.y*ux;
            float oc = (1.0f-cs)*kd;
            mx = ux*cs + cx*sn + a.x*oc;
            my = uy*cs + cy*sn + a.y*oc;
            mz = uz*cs + cz*sn + a.z*oc;
        }
        ba[b] = 1.0f - (mx*ux+my*uy+mz*uz);
        pos[cj*3+0] = pos[pj*3+0] + mx*bl;
        pos[cj*3+1] = pos[pj*3+1] + my*bl;
        pos[cj*3+2] = pos[pj*3+2] + mz*bl;
    }

    {
        float4* dst = (float4*)(out + (size_t)gid*48);
        #pragma unroll
        for (int i=0;i<12;i++) dst[i] = posv[i];
    }
    {
        float* bd = out + (size_t)NS*TL*48 + (size_t)gid*15;
        #pragma unroll
        for (int b=0;b<15;b++) bd[b] = ba[b];
    }
}

extern "C" void kernel_launch(void* const* d_in, const int* in_sizes, int n_in,
                              void* d_out, int out_size, void* d_ws, size_t ws_size,
                              hipStream_t stream)
{
    const float* x5    = (const float*)d_in[0];
    const float* noise = (const float*)d_in[1];
    const float* enc_w = (const float*)d_in[2];
    const float* enc_b = (const float*)d_in[3];
    const float* enc_g = (const float*)d_in[4];
    const float* enc_bb= (const float*)d_in[5];
    const float* ln_a  = (const float*)d_in[6];
    const float* ln_b  = (const float*)d_in[7];
    const float* wq = (const float*)d_in[8];
    const float* bq = (const float*)d_in[9];
    const float* wk = (const float*)d_in[10];
    const float* bk = (const float*)d_in[11];
    const float* wv = (const float*)d_in[12];
    const float* bv = (const float*)d_in[13];
    const float* wo = (const float*)d_in[14];
    const float* bo = (const float*)d_in[15];
    const float* w1 = (const float*)d_in[16];
    const float* b1 = (const float*)d_in[17];
    const float* g1 = (const float*)d_in[18];
    const float* bb1= (const float*)d_in[19];
    const float* w2 = (const float*)d_in[20];
    const float* b2 = (const float*)d_in[21];
    float* out = (float*)d_out;

    float* ws = (float*)d_ws;
    float* y2 = ws;                              // 2048*1488 f32 = 12.2 MB
    float* at = y2 + (size_t)NS*KD;              // 2048*60   f32 =  0.5 MB
    float* y3p = out;                            // gemm1 partials scratch in d_out
                                                 // (6*2048*256 f32 = 12.6 MB < 41.8 MB; pose overwrites later)

    attn_kernel<<<NS/2, 64, 0, stream>>>(x5, noise, enc_w, enc_b, enc_g, enc_bb,
                                         ln_a, ln_b, wq,bq,wk,bk,wv,bv,wo,bo, y2);
    gemm1_kernel<<<128*KSP, 256, 0, stream>>>(y2, w1, y3p);
    head_kernel<<<128, 256, 0, stream>>>(y3p, w2, b2, b1, g1, bb1, at);
    pose_kernel<<<(NS*TL+255)/256, 256, 0, stream>>>(x5, at, out);

    (void)in_sizes; (void)n_in; (void)out_size; (void)ws_size;
}

// Round 5
// 284.007 us; speedup vs baseline: 1.2758x; 1.2758x over previous
//
#include <hip/hip_runtime.h>
#include <math.h>

#define NS   2048
#define TL   81
#define NBN  15
#define DA   48
#define SQL  31
#define KD   1488   // SEQ*D_ATT
#define DL   256
#define MID  40

#define INV_SQRT_BN 0.99999500003749969f   // 1/sqrt(1+1e-5)
#define SCALE_ATT   0.35355339059327373f   // 1/sqrt(8)

// ---------------- Kernel 1 v5: lane=s, head-split across waves, LDS-staged weights ----------------
// Block = 256 (4 waves), 4 samples/block, grid 512 (2 blocks/CU).
// wave w: pair = w>>1 (samples bx*4+pair*2 +{0,1}), head-half = (w&1)*3 .. +2.
// v5 fix: params staged with a grid-stride loop (v4 wrote only sP[0..255] — garbage LN/biases).
__global__ __launch_bounds__(256)
void attn_kernel(const float* __restrict__ x5, const float* __restrict__ noise,
                 const float* __restrict__ enc_w, const float* __restrict__ enc_b,
                 const float* __restrict__ enc_g, const float* __restrict__ enc_bb,
                 const float* __restrict__ ln_a, const float* __restrict__ ln_b,
                 const float* __restrict__ wq, const float* __restrict__ bq,
                 const float* __restrict__ wk, const float* __restrict__ bk,
                 const float* __restrict__ wv, const float* __restrict__ bv,
                 const float* __restrict__ wo, const float* __restrict__ bo,
                 float* __restrict__ y2)
{
    __shared__ __align__(16) float sW[3*2304];   // wq|wk|wv, row-major [j_global][c]
    __shared__ __align__(16) float sWo[2304];    // wo [f][c]
    __shared__ __align__(16) float sKV[4*1536];  // per-wave: K[2][32][12] then V[2][32][12]
                                                 // reused after heads as sO[48][128]
    __shared__ float sP[576];                    // params

    const int tid  = threadIdx.x;
    const int lane = tid & 63;
    const int wv_  = tid >> 6;
    const int pair = wv_ >> 1;
    const int hbase= (wv_ & 1)*3;
    const int smp  = lane >> 5;
    const int s    = lane & 31;
    const int scl  = (s < 31) ? s : 30;
    const int n    = blockIdx.x*4 + pair*2 + smp;

    // ---- stage weights + params ----
    #pragma unroll
    for (int l=0; l<9; l++){
        int id = tid + l*256;                    // 0..2303
        sW[id]        = wq[id];
        sW[2304 + id] = wk[id];
        sW[4608 + id] = wv[id];
        sWo[id]       = wo[id];
    }
    #pragma unroll
    for (int l=0; l<3; l++){
        int id = tid + l*256;                    // 0..767
        if (id < 576){
            float v;
            if      (id < 144) v = enc_w[id];
            else if (id < 192) v = enc_b[id-144];
            else if (id < 240) v = enc_g[id-192];
            else if (id < 288) v = enc_bb[id-240];
            else if (id < 336) v = ln_a[id-288];
            else if (id < 384) v = ln_b[id-336];
            else if (id < 432) v = bq[id-384];
            else if (id < 480) v = bk[id-432];
            else if (id < 528) v = bv[id-480];
            else               v = bo[id-528];
            sP[id] = v;
        }
    }

    // ---- per-lane 3-vector input ----
    float x0, x1, x2;
    if (scl < 16){
        const float* base = x5 + ((size_t)n*TL + MID)*48;
        x0 = base[scl*3+0] - base[0];
        x1 = base[scl*3+1] - base[1];
        x2 = base[scl*3+2] - base[2];
    } else {
        const float* nb = noise + (size_t)n*45 + (scl*3 - 48);
        x0 = nb[0]; x1 = nb[1]; x2 = nb[2];
    }
    __syncthreads();

    // ---- encoder + BN + relu (params broadcast from LDS) ----
    float y[48];
    #pragma unroll
    for (int f=0; f<48; f++){
        float a = sP[144+f] + x0*sP[f*3+0] + x1*sP[f*3+1] + x2*sP[f*3+2];
        float v = a*(sP[192+f]*INV_SQRT_BN) + sP[240+f];
        y[f] = fmaxf(v, 0.0f);
    }

    // ---- layer norm (lane-local) ----
    float mean = 0.f;
    #pragma unroll
    for (int f=0; f<48; f++) mean += y[f];
    mean *= (1.0f/48.0f);
    float vs = 0.f;
    #pragma unroll
    for (int f=0; f<48; f++){ float d = y[f]-mean; vs += d*d; }
    const float rstd = 1.0f/(sqrtf(vs*(1.0f/47.0f)) + 1e-6f);
    float h[48];
    #pragma unroll
    for (int f=0; f<48; f++) h[f] = sP[288+f]*(y[f]-mean)*rstd + sP[336+f];

    // ---- 3 heads per wave ----
    float o[48];
    #pragma unroll
    for (int f=0; f<48; f++) o[f] = 0.f;

    float* kvb = sKV + wv_*1536 + smp*384;       // this wave+sample's K base; V at +768

    #pragma unroll 1
    for (int hh=0; hh<3; hh++){
        const int hd = hbase + hh;
        float q8[8], k8[8], v8[8];
        #pragma unroll
        for (int j=0; j<8; j++){
            q8[j] = sP[384+hd*8+j]; k8[j] = sP[432+hd*8+j]; v8[j] = sP[480+hd*8+j];
        }
        // QKV projection: weights via wave-uniform b128 broadcasts
        #pragma unroll 2
        for (int j=0; j<8; j++){
            const float* wqr = sW +        (hd*8+j)*48;
            const float* wkr = sW + 2304 + (hd*8+j)*48;
            const float* wvr = sW + 4608 + (hd*8+j)*48;
            float aq = q8[j], ak = k8[j], av = v8[j];
            #pragma unroll
            for (int c4=0; c4<12; c4++){
                float4 wq4 = *(const float4*)(wqr + c4*4);
                float4 wk4 = *(const float4*)(wkr + c4*4);
                float4 wv4 = *(const float4*)(wvr + c4*4);
                float h0 = h[c4*4+0], h1 = h[c4*4+1], h2 = h[c4*4+2], h3 = h[c4*4+3];
                aq += h0*wq4.x + h1*wq4.y + h2*wq4.z + h3*wq4.w;
                ak += h0*wk4.x + h1*wk4.y + h2*wk4.z + h3*wk4.w;
                av += h0*wv4.x + h1*wv4.y + h2*wv4.z + h3*wv4.w;
            }
            q8[j] = aq; k8[j] = ak; v8[j] = av;
        }

        // stage K,V (own row; same-wave in-order DS pipeline: no barrier needed)
        {
            float* kr = kvb + s*12;
            float* vr = kvb + 768 + s*12;
            float4 t0, t1;
            t0.x=k8[0]; t0.y=k8[1]; t0.z=k8[2]; t0.w=k8[3];
            t1.x=k8[4]; t1.y=k8[5]; t1.z=k8[6]; t1.w=k8[7];
            *(float4*)(kr) = t0; *(float4*)(kr+4) = t1;
            t0.x=v8[0]; t0.y=v8[1]; t0.z=v8[2]; t0.w=v8[3];
            t1.x=v8[4]; t1.y=v8[5]; t1.z=v8[6]; t1.w=v8[7];
            *(float4*)(vr) = t0; *(float4*)(vr+4) = t1;
        }

        // scores
        float sc[31];
        float mx = -1e30f;
        #pragma unroll
        for (int ki=0; ki<31; ki++){
            const float* kp = kvb + ki*12;
            float4 ka = *(const float4*)(kp);
            float4 kb = *(const float4*)(kp+4);
            float d = q8[0]*ka.x + q8[1]*ka.y + q8[2]*ka.z + q8[3]*ka.w
                    + q8[4]*kb.x + q8[5]*kb.y + q8[6]*kb.z + q8[7]*kb.w;
            d *= SCALE_ATT;
            sc[ki] = d;
            mx = fmaxf(mx, d);
        }
        float ssum = 0.f;
        #pragma unroll
        for (int ki=0; ki<31; ki++){
            float e = __expf(sc[ki]-mx);
            sc[ki] = e; ssum += e;
        }
        const float rin = 1.0f/ssum;

        float c8[8];
        #pragma unroll
        for (int j=0; j<8; j++) c8[j] = 0.f;
        #pragma unroll
        for (int ki=0; ki<31; ki++){
            const float* vp = kvb + 768 + ki*12;
            float4 va = *(const float4*)(vp);
            float4 vb = *(const float4*)(vp+4);
            float p = sc[ki];
            c8[0] += p*va.x; c8[1] += p*va.y; c8[2] += p*va.z; c8[3] += p*va.w;
            c8[4] += p*vb.x; c8[5] += p*vb.y; c8[6] += p*vb.z; c8[7] += p*vb.w;
        }
        #pragma unroll
        for (int j=0; j<8; j++) c8[j] *= rin;

        // fold ctx into o via wo (wave-uniform b128 broadcasts)
        #pragma unroll 4
        for (int f=0; f<48; f++){
            const float* wor = sWo + f*48 + hd*8;
            float4 wa = *(const float4*)(wor);
            float4 wb = *(const float4*)(wor+4);
            o[f] += c8[0]*wa.x + c8[1]*wa.y + c8[2]*wa.z + c8[3]*wa.w
                  + c8[4]*wb.x + c8[5]*wb.y + c8[6]*wb.z + c8[7]*wb.w;
        }
    }

    // ---- combine head-halves: waves 1,3 dump o into sO (aliases dead sKV), waves 0,2 sum+store ----
    __syncthreads();
    float* sO = sKV;                              // [f][128], col = pair*64 + lane
    const int col = pair*64 + lane;
    if (wv_ & 1){
        #pragma unroll
        for (int f=0; f<48; f++) sO[f*128 + col] = o[f];
    }
    __syncthreads();
    if (!(wv_ & 1) && s < 31){
        float* dst = y2 + (size_t)n*KD + s*48;
        #pragma unroll
        for (int f4=0; f4<12; f4++){
            float4 v;
            v.x = y[f4*4+0] + o[f4*4+0] + sO[(f4*4+0)*128+col] + sP[528+f4*4+0];
            v.y = y[f4*4+1] + o[f4*4+1] + sO[(f4*4+1)*128+col] + sP[528+f4*4+1];
            v.z = y[f4*4+2] + o[f4*4+2] + sO[(f4*4+2)*128+col] + sP[528+f4*4+2];
            v.w = y[f4*4+3] + o[f4*4+3] + sO[(f4*4+3)*128+col] + sP[528+f4*4+3];
            *(float4*)(dst + f4*4) = v;
        }
    }
}

// ---------------- Kernel 2: raw dot C = y2 @ w1^T, K-split 6, partials -> d_out scratch ----------------
#define KSP 6
#define KPS 248     // 1488/6
#define KCH 8

__global__ __launch_bounds__(256)
void gemm1_kernel(const float* __restrict__ y2, const float* __restrict__ w1,
                  float* __restrict__ y3p)
{
    __shared__ __align__(16) float sB[KCH*256];     // [kk][n]  8KB
    __shared__ __align__(16) float sA[KCH*20];      // [kk][m]  640B
    const int tid = threadIdx.x;
    const int bx = blockIdx.x;                      // 768 blocks
    const int m0 = (bx & 127) * 16;
    const int split = bx >> 7;                      // 0..5
    const int ks0 = split * KPS;
    const int c0 = (tid & 15)*4 + (tid >> 6)*64;    // output cols c0..c0+3
    const int r0 = ((tid >> 4) & 3)*4;              // output rows r0..r0+3

    const int bn = tid >> 1;
    const int bg = (tid & 1)*4;
    const int ar = tid >> 1;
    const int ag = (tid & 1)*4;

    float acc[4][4];
    #pragma unroll
    for (int i=0;i<4;i++)
        #pragma unroll
        for (int j=0;j<4;j++) acc[i][j]=0.f;

    for (int ch=0; ch<31; ch++){
        const int k0 = ks0 + ch*KCH;
        float4 b0v = *(const float4*)(w1 + (size_t)bn*KD        + k0 + bg);
        float4 b1v = *(const float4*)(w1 + (size_t)(bn+128)*KD  + k0 + bg);
        float4 av;
        if (tid < 32) av = *(const float4*)(y2 + (size_t)(m0+ar)*KD + k0 + ag);
        __syncthreads();
        sB[(bg+0)*256 + bn] = b0v.x;  sB[(bg+1)*256 + bn] = b0v.y;
        sB[(bg+2)*256 + bn] = b0v.z;  sB[(bg+3)*256 + bn] = b0v.w;
        sB[(bg+0)*256 + bn+128] = b1v.x;  sB[(bg+1)*256 + bn+128] = b1v.y;
        sB[(bg+2)*256 + bn+128] = b1v.z;  sB[(bg+3)*256 + bn+128] = b1v.w;
        if (tid < 32){
            sA[(ag+0)*20 + ar] = av.x;  sA[(ag+1)*20 + ar] = av.y;
            sA[(ag+2)*20 + ar] = av.z;  sA[(ag+3)*20 + ar] = av.w;
        }
        __syncthreads();
        #pragma unroll
        for (int kk=0; kk<KCH; kk++){
            float4 b = *(const float4*)(sB + kk*256 + c0);
            float4 a = *(const float4*)(sA + kk*20 + r0);
            acc[0][0] += a.x*b.x; acc[0][1] += a.x*b.y; acc[0][2] += a.x*b.z; acc[0][3] += a.x*b.w;
            acc[1][0] += a.y*b.x; acc[1][1] += a.y*b.y; acc[1][2] += a.y*b.z; acc[1][3] += a.y*b.w;
            acc[2][0] += a.z*b.x; acc[2][1] += a.z*b.y; acc[2][2] += a.z*b.z; acc[2][3] += a.z*b.w;
            acc[3][0] += a.w*b.x; acc[3][1] += a.w*b.y; acc[3][2] += a.w*b.z; acc[3][3] += a.w*b.w;
        }
    }

    float* dst = y3p + (size_t)split*NS*DL;
    #pragma unroll
    for (int i=0;i<4;i++){
        float4 v; v.x=acc[i][0]; v.y=acc[i][1]; v.z=acc[i][2]; v.w=acc[i][3];
        *(float4*)(dst + (size_t)(m0+r0+i)*DL + c0) = v;
    }
}

// ---------------- Kernel 3: reduce splits + bias/BN/leaky; y4 = leaky(y3 @ w2^T + b2); axis/theta ----------------
__global__ __launch_bounds__(256)
void head_kernel(const float* __restrict__ y3p, const float* __restrict__ w2,
                 const float* __restrict__ b2, const float* __restrict__ b1,
                 const float* __restrict__ g1, const float* __restrict__ bb1,
                 float* __restrict__ at)
{
    __shared__ float swc[64*60];
    __shared__ __align__(16) float sy3[16*256];
    __shared__ float sy4[16*61];
    const int tid = threadIdx.x;
    const int n0 = blockIdx.x * 16;

    #pragma unroll
    for (int l=0;l<4;l++){
        int idx = tid + l*256;
        int s = idx >> 6, i4 = (idx & 63) << 2;
        const float* src = y3p + (size_t)(n0+s)*256 + i4;
        float4 v = *(const float4*)(src);
        #pragma unroll
        for (int sl=1; sl<6; sl++){
            float4 p = *(const float4*)(src + (size_t)sl*NS*DL);
            v.x += p.x; v.y += p.y; v.z += p.z; v.w += p.w;
        }
        const float4 vb = *(const float4*)(b1 + i4);
        const float4 vg = *(const float4*)(g1 + i4);
        const float4 vsb = *(const float4*)(bb1 + i4);
        v.x = (v.x + vb.x)*(vg.x*INV_SQRT_BN) + vsb.x;  v.x = v.x>=0.f? v.x : 0.01f*v.x;
        v.y = (v.y + vb.y)*(vg.y*INV_SQRT_BN) + vsb.y;  v.y = v.y>=0.f? v.y : 0.01f*v.y;
        v.z = (v.z + vb.z)*(vg.z*INV_SQRT_BN) + vsb.z;  v.z = v.z>=0.f? v.z : 0.01f*v.z;
        v.w = (v.w + vb.w)*(vg.w*INV_SQRT_BN) + vsb.w;  v.w = v.w>=0.f? v.w : 0.01f*v.w;
        *(float4*)(sy3 + s*256 + i4) = v;
    }

    float acc[4]; int ss[4], mm[4];
    #pragma unroll
    for (int l=0;l<4;l++){
        int uu = tid + l*256;
        ss[l]=0; mm[l]=0; acc[l]=0.f;
        if (uu < 960){ ss[l]=uu/60; mm[l]=uu-ss[l]*60; acc[l]=b2[mm[l]]; }
    }

    for (int ch=0; ch<4; ch++){
        const int i0 = ch*64;
        __syncthreads();
        #pragma unroll
        for (int l=0;l<15;l++){
            int idx = tid + l*256;
            int m = idx >> 6, io = idx & 63;
            swc[io*60 + m] = w2[(size_t)m*256 + i0 + io];
        }
        __syncthreads();
        #pragma unroll
        for (int l=0;l<4;l++){
            int uu = tid + l*256;
            if (uu < 960){
                const float* yy = sy3 + ss[l]*256 + i0;
                float a = acc[l];
                #pragma unroll 8
                for (int io=0; io<64; io++) a += yy[io]*swc[io*60 + mm[l]];
                acc[l] = a;
            }
        }
    }
    __syncthreads();
    #pragma unroll
    for (int l=0;l<4;l++){
        int uu = tid + l*256;
        if (uu < 960){
            float a = acc[l];
            sy4[ss[l]*61 + mm[l]] = a>=0.f? a : 0.01f*a;
        }
    }
    __syncthreads();
    if (tid < 240){
        int s = tid/15, b = tid - s*15;
        const float* y4 = sy4 + s*61 + b*4;
        float ax=y4[0], ay=y4[1], az=y4[2], th=y4[3];
        float nr = sqrtf(ax*ax+ay*ay+az*az);
        float4 o;
        o.x = ax/nr; o.y = ay/nr; o.z = az/nr; o.w = th/81.0f;
        *(float4*)(at + (size_t)(n0+s)*60 + b*4) = o;
    }
}

// ---------------- Kernel 4: per-(n,t) Rodrigues + FK + ba_diff ----------------
__global__ __launch_bounds__(256)
void pose_kernel(const float* __restrict__ x5, const float* __restrict__ at,
                 float* __restrict__ out)
{
    const int gid = blockIdx.x*256 + threadIdx.x;
    if (gid >= NS*TL) return;
    const int n = gid / TL;
    const int t = gid - n*TL;
    const float ft = (float)t;

    float4 pv[12];
    {
        const float4* src = (const float4*)(x5 + (size_t)gid*48);
        #pragma unroll
        for (int i=0;i<12;i++) pv[i] = src[i];
    }
    float* p = (float*)pv;
    const float4* ab = (const float4*)(at + (size_t)n*60);

    float4 posv[12];
    float* pos = (float*)posv;
    pos[0]=p[0]; pos[1]=p[1]; pos[2]=p[2];
    float ba[15];

    const int PJ[15] = {0,1,2,0,4,5,0,7,8,9,8,11,12,8,14};
    const int CJ[15] = {1,2,3,4,5,6,7,8,9,10,11,12,13,14,15};

    #pragma unroll
    for (int b=0;b<15;b++){
        const int pj = PJ[b], cj = CJ[b];
        float bx = p[cj*3+0]-p[pj*3+0];
        float by = p[cj*3+1]-p[pj*3+1];
        float bz = p[cj*3+2]-p[pj*3+2];
        float bl = sqrtf(bx*bx+by*by+bz*bz);
        float ux = bx/bl, uy = by/bl, uz = bz/bl;
        float mx, my, mz;
        if (b==6 || b==7){
            mx=ux; my=uy; mz=uz;
        } else {
            float4 a = ab[b];
            float ang = a.w * ft;
            float cs, sn;
            __sincosf(ang, &sn, &cs);
            float kd = a.x*ux + a.y*uy + a.z*uz;
            float cx = a.y*uz - a.z*uy;
            float cy = a.z*ux - a.x*uz;
            float cz = a.x*uy - a.y*ux;
            float oc = (1.0f-cs)*kd;
            mx = ux*cs + cx*sn + a.x*oc;
            my = uy*cs + cy*sn + a.y*oc;
            mz = uz*cs + cz*sn + a.z*oc;
        }
        ba[b] = 1.0f - (mx*ux+my*uy+mz*uz);
        pos[cj*3+0] = pos[pj*3+0] + mx*bl;
        pos[cj*3+1] = pos[pj*3+1] + my*bl;
        pos[cj*3+2] = pos[pj*3+2] + mz*bl;
    }

    {
        float4* dst = (float4*)(out + (size_t)gid*48);
        #pragma unroll
        for (int i=0;i<12;i++) dst[i] = posv[i];
    }
    {
        float* bd = out + (size_t)NS*TL*48 + (size_t)gid*15;
        #pragma unroll
        for (int b=0;b<15;b++) bd[b] = ba[b];
    }
}

extern "C" void kernel_launch(void* const* d_in, const int* in_sizes, int n_in,
                              void* d_out, int out_size, void* d_ws, size_t ws_size,
                              hipStream_t stream)
{
    const float* x5    = (const float*)d_in[0];
    const float* noise = (const float*)d_in[1];
    const float* enc_w = (const float*)d_in[2];
    const float* enc_b = (const float*)d_in[3];
    const float* enc_g = (const float*)d_in[4];
    const float* enc_bb= (const float*)d_in[5];
    const float* ln_a  = (const float*)d_in[6];
    const float* ln_b  = (const float*)d_in[7];
    const float* wq = (const float*)d_in[8];
    const float* bq = (const float*)d_in[9];
    const float* wk = (const float*)d_in[10];
    const float* bk = (const float*)d_in[11];
    const float* wv = (const float*)d_in[12];
    const float* bv = (const float*)d_in[13];
    const float* wo = (const float*)d_in[14];
    const float* bo = (const float*)d_in[15];
    const float* w1 = (const float*)d_in[16];
    const float* b1 = (const float*)d_in[17];
    const float* g1 = (const float*)d_in[18];
    const float* bb1= (const float*)d_in[19];
    const float* w2 = (const float*)d_in[20];
    const float* b2 = (const float*)d_in[21];
    float* out = (float*)d_out;

    float* ws = (float*)d_ws;
    float* y2 = ws;                              // 2048*1488 f32 = 12.2 MB
    float* at = y2 + (size_t)NS*KD;              // 2048*60   f32 =  0.5 MB
    float* y3p = out;                            // gemm1 partials scratch in d_out (12.6 < 41.8 MB)

    attn_kernel<<<NS/4, 256, 0, stream>>>(x5, noise, enc_w, enc_b, enc_g, enc_bb,
                                          ln_a, ln_b, wq,bq,wk,bk,wv,bv,wo,bo, y2);
    gemm1_kernel<<<128*KSP, 256, 0, stream>>>(y2, w1, y3p);
    head_kernel<<<128, 256, 0, stream>>>(y3p, w2, b2, b1, g1, bb1, at);
    pose_kernel<<<(NS*TL+255)/256, 256, 0, stream>>>(x5, at, out);

    (void)in_sizes; (void)n_in; (void)out_size; (void)ws_size;
}

// Round 6
// 260.248 us; speedup vs baseline: 1.3923x; 1.0913x over previous
//
#include <hip/hip_runtime.h>
#include <math.h>

#define NS   2048
#define TL   81
#define DA   48
#define SQL  31
#define KD   1488      // SEQ*D_ATT
#define DL   256
#define MID  40
#define QROWS 63488    // NS*SQL

#define INV_SQRT_BN 0.99999500003749969f   // 1/sqrt(1+1e-5)
#define SCALE_ATT   0.35355339059327373f   // 1/sqrt(8)

// ---------------- K1: enc+LN (per 128-row tile) + QKV GEMM (M=63488,N=144,K=48) ----------------
// 496 blocks x 256 thr. LDS: h[128][52] + Wqkv[144][52]. Thread tile 8 rows x 9 cols,
// rows {ty+16i}, cols {tx+16j}. All LDS frag reads audited <=2-way conflicts.
__global__ __launch_bounds__(256)
void qkv_kernel(const float* __restrict__ x5, const float* __restrict__ noise,
                const float* __restrict__ enc_w, const float* __restrict__ enc_b,
                const float* __restrict__ enc_g, const float* __restrict__ enc_bb,
                const float* __restrict__ ln_a, const float* __restrict__ ln_b,
                const float* __restrict__ wq, const float* __restrict__ bq,
                const float* __restrict__ wk, const float* __restrict__ bk,
                const float* __restrict__ wv, const float* __restrict__ bv,
                float* __restrict__ qkv)
{
    __shared__ __align__(16) float sH[128*52];
    __shared__ __align__(16) float sW[144*52];
    const int tid = threadIdx.x;
    const int m0 = blockIdx.x * 128;

    // stage Wqkv as [col][k] (col<48:q, <96:k, <144:v), 1728 b128 slots
    #pragma unroll
    for (int l=0; l<7; l++){
        int id = tid + l*256;
        if (id < 1728){
            int col = id / 12, kq = id - col*12;
            const float* src = (col < 48) ? (wq + col*48)
                             : (col < 96) ? (wk + (col-48)*48)
                                          : (wv + (col-96)*48);
            *(float4*)(&sW[col*52 + kq*4]) = *(const float4*)(src + kq*4);
        }
    }

    // phase 1: rows -> h in LDS (threads 0..127, one row each)
    if (tid < 128){
        const int grow = m0 + tid;
        const int n = grow / 31, s = grow - n*31;
        float x0, x1, x2;
        if (s < 16){
            const float* base = x5 + ((size_t)n*TL + MID)*48;
            x0 = base[s*3+0]-base[0]; x1 = base[s*3+1]-base[1]; x2 = base[s*3+2]-base[2];
        } else {
            const float* nb = noise + (size_t)n*45 + (s*3-48);
            x0 = nb[0]; x1 = nb[1]; x2 = nb[2];
        }
        float y[48]; float mean = 0.f;
        #pragma unroll
        for (int f=0; f<48; f++){
            float a = enc_b[f] + x0*enc_w[f*3+0] + x1*enc_w[f*3+1] + x2*enc_w[f*3+2];
            float v = a*(enc_g[f]*INV_SQRT_BN) + enc_bb[f];
            y[f] = fmaxf(v, 0.0f);
            mean += y[f];
        }
        mean *= (1.0f/48.0f);
        float vs = 0.f;
        #pragma unroll
        for (int f=0; f<48; f++){ float d = y[f]-mean; vs += d*d; }
        const float rstd = 1.0f/(sqrtf(vs*(1.0f/47.0f)) + 1e-6f);
        #pragma unroll
        for (int f=0; f<48; f++)
            sH[tid*52 + f] = ln_a[f]*(y[f]-mean)*rstd + ln_b[f];
    }
    __syncthreads();

    // phase 2: GEMM
    const int ty = tid >> 4, tx = tid & 15;
    float acc[8][9];
    #pragma unroll
    for (int i=0;i<8;i++)
        #pragma unroll
        for (int j=0;j<9;j++) acc[i][j] = 0.f;

    #pragma unroll
    for (int kq=0; kq<12; kq++){
        float4 a[8], b[9];
        #pragma unroll
        for (int i=0;i<8;i++) a[i] = *(const float4*)(&sH[(ty+16*i)*52 + kq*4]);
        #pragma unroll
        for (int j=0;j<9;j++) b[j] = *(const float4*)(&sW[(tx+16*j)*52 + kq*4]);
        #pragma unroll
        for (int i=0;i<8;i++)
            #pragma unroll
            for (int j=0;j<9;j++)
                acc[i][j] += a[i].x*b[j].x + a[i].y*b[j].y + a[i].z*b[j].z + a[i].w*b[j].w;
    }

    #pragma unroll
    for (int i=0;i<8;i++){
        const size_t grow = m0 + ty + 16*i;
        #pragma unroll
        for (int j=0;j<9;j++){
            int col = tx + 16*j;
            float bias = (col < 48) ? bq[col] : (col < 96) ? bk[col-48] : bv[col-96];
            qkv[grow*144 + col] = acc[i][j] + bias;
        }
    }
}

// ---------------- K2: attention core (scores/softmax/PV) -> raw ctx ----------------
// Block 256 = 4 waves. wave=(pair, head-half); lane: smp=lane>>5, s=lane&31.
// K,V staged per (wave,smp) in LDS (same-wave DS ordering, no barrier).
__global__ __launch_bounds__(256)
void attn_kernel(const float* __restrict__ qkv, float* __restrict__ ctx)
{
    __shared__ __align__(16) float sKV[4*2*768];   // [wave][smp]: K 32x12 | V 32x12

    const int tid  = threadIdx.x;
    const int lane = tid & 63;
    const int wv_  = tid >> 6;
    const int pair = wv_ >> 1;
    const int hh0  = (wv_ & 1);          // head-half
    const int smp  = lane >> 5;
    const int s    = lane & 31;
    const int scl  = (s < 31) ? s : 30;
    const int n    = blockIdx.x*4 + pair*2 + smp;
    const size_t row = (size_t)n*31 + scl;

    float* kvb = sKV + (wv_*2 + smp)*768;
    float ctx24[24];

    #pragma unroll 1
    for (int hh=0; hh<3; hh++){
        const int hd = hh0*3 + hh;
        const float* qp = qkv + row*144 + hd*8;
        const float4 q0 = *(const float4*)(qp);
        const float4 q1 = *(const float4*)(qp+4);
        const float4 k0 = *(const float4*)(qp+48);
        const float4 k1 = *(const float4*)(qp+52);
        const float4 v0 = *(const float4*)(qp+96);
        const float4 v1 = *(const float4*)(qp+100);

        *(float4*)(kvb + s*12)       = k0;
        *(float4*)(kvb + s*12 + 4)   = k1;
        *(float4*)(kvb + 384 + s*12)     = v0;
        *(float4*)(kvb + 384 + s*12 + 4) = v1;

        float sc[31]; float mx = -1e30f;
        #pragma unroll
        for (int ki=0; ki<31; ki++){
            const float4 ka = *(const float4*)(kvb + ki*12);
            const float4 kb = *(const float4*)(kvb + ki*12 + 4);
            float d = q0.x*ka.x + q0.y*ka.y + q0.z*ka.z + q0.w*ka.w
                    + q1.x*kb.x + q1.y*kb.y + q1.z*kb.z + q1.w*kb.w;
            d *= SCALE_ATT;
            sc[ki] = d; mx = fmaxf(mx, d);
        }
        float ssum = 0.f;
        #pragma unroll
        for (int ki=0; ki<31; ki++){ float e = __expf(sc[ki]-mx); sc[ki]=e; ssum += e; }
        const float rin = 1.0f/ssum;

        float c8[8];
        #pragma unroll
        for (int j=0;j<8;j++) c8[j] = 0.f;
        #pragma unroll
        for (int ki=0; ki<31; ki++){
            const float4 va = *(const float4*)(kvb + 384 + ki*12);
            const float4 vb = *(const float4*)(kvb + 384 + ki*12 + 4);
            const float p = sc[ki];
            c8[0] += p*va.x; c8[1] += p*va.y; c8[2] += p*va.z; c8[3] += p*va.w;
            c8[4] += p*vb.x; c8[5] += p*vb.y; c8[6] += p*vb.z; c8[7] += p*vb.w;
        }
        #pragma unroll
        for (int j=0;j<8;j++) ctx24[hh*8+j] = c8[j]*rin;
    }

    if (s < 31){
        float* dst = ctx + ((size_t)n*31 + s)*48 + hh0*24;
        #pragma unroll
        for (int q=0; q<6; q++){
            float4 v;
            v.x = ctx24[q*4+0]; v.y = ctx24[q*4+1];
            v.z = ctx24[q*4+2]; v.w = ctx24[q*4+3];
            *(float4*)(dst + q*4) = v;
        }
    }
}

// ---------------- K3: y2 = y(recomputed) + ctx @ wo^T + bo ----------------
// 496 blocks, M-tile 128, N=48. Thread tile 8 rows x 3 cols.
__global__ __launch_bounds__(256)
void proj_kernel(const float* __restrict__ ctxg, const float* __restrict__ wo,
                 const float* __restrict__ bo,
                 const float* __restrict__ x5, const float* __restrict__ noise,
                 const float* __restrict__ enc_w, const float* __restrict__ enc_b,
                 const float* __restrict__ enc_g, const float* __restrict__ enc_bb,
                 float* __restrict__ y2)
{
    __shared__ __align__(16) float sC[128*52];
    __shared__ __align__(16) float sWo[48*52];
    const int tid = threadIdx.x;
    const int m0 = blockIdx.x * 128;

    #pragma unroll
    for (int l=0; l<6; l++){
        int id = tid + l*256;                 // 0..1535
        int r = id / 12, kq = id - r*12;
        *(float4*)(&sC[r*52 + kq*4]) = *(const float4*)(ctxg + (size_t)(m0+r)*48 + kq*4);
    }
    #pragma unroll
    for (int l=0; l<3; l++){
        int id = tid + l*256;
        if (id < 576){
            int c = id / 12, kq = id - c*12;
            *(float4*)(&sWo[c*52 + kq*4]) = *(const float4*)(wo + c*48 + kq*4);
        }
    }
    __syncthreads();

    const int ty = tid >> 4, tx = tid & 15;
    float acc[8][3];
    #pragma unroll
    for (int i=0;i<8;i++){ acc[i][0]=0.f; acc[i][1]=0.f; acc[i][2]=0.f; }

    #pragma unroll
    for (int kq=0; kq<12; kq++){
        float4 a[8], b[3];
        #pragma unroll
        for (int i=0;i<8;i++) a[i] = *(const float4*)(&sC[(ty+16*i)*52 + kq*4]);
        #pragma unroll
        for (int j=0;j<3;j++) b[j] = *(const float4*)(&sWo[(tx+16*j)*52 + kq*4]);
        #pragma unroll
        for (int i=0;i<8;i++)
            #pragma unroll
            for (int j=0;j<3;j++)
                acc[i][j] += a[i].x*b[j].x + a[i].y*b[j].y + a[i].z*b[j].z + a[i].w*b[j].w;
    }

    // per-column enc params (3 cols)
    float cw0[3],cw1[3],cw2[3],cb[3],cg[3],cbb[3],cbo[3];
    #pragma unroll
    for (int j=0;j<3;j++){
        int c = tx + 16*j;
        cw0[j]=enc_w[c*3+0]; cw1[j]=enc_w[c*3+1]; cw2[j]=enc_w[c*3+2];
        cb[j]=enc_b[c]; cg[j]=enc_g[c]*INV_SQRT_BN; cbb[j]=enc_bb[c]; cbo[j]=bo[c];
    }

    #pragma unroll
    for (int i=0;i<8;i++){
        const int grow = m0 + ty + 16*i;
        const int n = grow / 31, s = grow - n*31;
        float x0, x1, x2;
        if (s < 16){
            const float* base = x5 + ((size_t)n*TL + MID)*48;
            x0 = base[s*3+0]-base[0]; x1 = base[s*3+1]-base[1]; x2 = base[s*3+2]-base[2];
        } else {
            const float* nb = noise + (size_t)n*45 + (s*3-48);
            x0 = nb[0]; x1 = nb[1]; x2 = nb[2];
        }
        #pragma unroll
        for (int j=0;j<3;j++){
            int c = tx + 16*j;
            float e = cb[j] + x0*cw0[j] + x1*cw1[j] + x2*cw2[j];
            float yv = fmaxf(e*cg[j] + cbb[j], 0.0f);
            y2[(size_t)grow*48 + c] = yv + acc[i][j] + cbo[j];
        }
    }
}

// ---------------- K4: gemm1 v3 — C = y2 @ w1^T, M-tile 64, N=256, K-split 12 ----------------
#define KSP 12
#define KPS 124
__global__ __launch_bounds__(256)
void gemm1_kernel(const float* __restrict__ y2, const float* __restrict__ w1,
                  float* __restrict__ y3p)
{
    __shared__ __align__(16) float sA[4*68];       // [kk][row+pad]
    __shared__ __align__(16) float sB[4*256];      // [kk][col]
    const int tid = threadIdx.x;
    const int bx  = blockIdx.x;                    // 384 = 32 m-tiles x 12 splits
    const int m0    = (bx & 31) * 64;
    const int split = bx >> 5;
    const int ks0   = split * KPS;

    const int wv_ = tid >> 6;
    const int lane = tid & 63;
    const int ty = lane >> 3, tx = lane & 7;
    const int r0 = ty*8;
    const int c0 = wv_*64 + tx*8;

    const int sr = tid >> 2, sk = tid & 3;         // A staging
    float acc[8][8];
    #pragma unroll
    for (int i=0;i<8;i++)
        #pragma unroll
        for (int j=0;j<8;j++) acc[i][j] = 0.f;

    for (int ch=0; ch<31; ch++){
        const int k0 = ks0 + ch*4;
        float av;
        if (tid < 256) av = y2[(size_t)(m0+sr)*KD + k0 + sk];
        float4 bv4 = *(const float4*)(w1 + (size_t)tid*KD + k0);
        __syncthreads();
        sA[sk*68 + sr] = av;
        sB[0*256 + tid] = bv4.x;
        sB[1*256 + tid] = bv4.y;
        sB[2*256 + tid] = bv4.z;
        sB[3*256 + tid] = bv4.w;
        __syncthreads();
        #pragma unroll
        for (int kk=0; kk<4; kk++){
            const float4 a0 = *(const float4*)(&sA[kk*68 + r0]);
            const float4 a1 = *(const float4*)(&sA[kk*68 + r0 + 4]);
            const float4 b0 = *(const float4*)(&sB[kk*256 + c0]);
            const float4 b1 = *(const float4*)(&sB[kk*256 + c0 + 4]);
            const float ar[8] = {a0.x,a0.y,a0.z,a0.w,a1.x,a1.y,a1.z,a1.w};
            const float br[8] = {b0.x,b0.y,b0.z,b0.w,b1.x,b1.y,b1.z,b1.w};
            #pragma unroll
            for (int i=0;i<8;i++)
                #pragma unroll
                for (int j=0;j<8;j++)
                    acc[i][j] += ar[i]*br[j];
        }
    }

    float* dst = y3p + (size_t)split*NS*DL;
    #pragma unroll
    for (int i=0;i<8;i++){
        float4 v0, v1;
        v0.x=acc[i][0]; v0.y=acc[i][1]; v0.z=acc[i][2]; v0.w=acc[i][3];
        v1.x=acc[i][4]; v1.y=acc[i][5]; v1.z=acc[i][6]; v1.w=acc[i][7];
        float* p = dst + (size_t)(m0+r0+i)*DL + c0;
        *(float4*)(p)   = v0;
        *(float4*)(p+4) = v1;
    }
}

// ---------------- K5: reduce 12 splits + bias/BN/leaky; y4 = leaky(y3 @ w2^T + b2); axis/theta ----------------
__global__ __launch_bounds__(256)
void head_kernel(const float* __restrict__ y3p, const float* __restrict__ w2,
                 const float* __restrict__ b2, const float* __restrict__ b1,
                 const float* __restrict__ g1, const float* __restrict__ bb1,
                 float* __restrict__ at)
{
    __shared__ float swc[64*60];
    __shared__ __align__(16) float sy3[16*256];
    __shared__ float sy4[16*61];
    const int tid = threadIdx.x;
    const int n0 = blockIdx.x * 16;

    #pragma unroll
    for (int l=0;l<4;l++){
        int idx = tid + l*256;
        int s = idx >> 6, i4 = (idx & 63) << 2;
        const float* src = y3p + (size_t)(n0+s)*256 + i4;
        float4 v = *(const float4*)(src);
        #pragma unroll
        for (int sl=1; sl<KSP; sl++){
            float4 p = *(const float4*)(src + (size_t)sl*NS*DL);
            v.x += p.x; v.y += p.y; v.z += p.z; v.w += p.w;
        }
        const float4 vb = *(const float4*)(b1 + i4);
        const float4 vg = *(const float4*)(g1 + i4);
        const float4 vsb = *(const float4*)(bb1 + i4);
        v.x = (v.x + vb.x)*(vg.x*INV_SQRT_BN) + vsb.x;  v.x = v.x>=0.f? v.x : 0.01f*v.x;
        v.y = (v.y + vb.y)*(vg.y*INV_SQRT_BN) + vsb.y;  v.y = v.y>=0.f? v.y : 0.01f*v.y;
        v.z = (v.z + vb.z)*(vg.z*INV_SQRT_BN) + vsb.z;  v.z = v.z>=0.f? v.z : 0.01f*v.z;
        v.w = (v.w + vb.w)*(vg.w*INV_SQRT_BN) + vsb.w;  v.w = v.w>=0.f? v.w : 0.01f*v.w;
        *(float4*)(sy3 + s*256 + i4) = v;
    }

    float acc[4]; int ss[4], mm[4];
    #pragma unroll
    for (int l=0;l<4;l++){
        int uu = tid + l*256;
        ss[l]=0; mm[l]=0; acc[l]=0.f;
        if (uu < 960){ ss[l]=uu/60; mm[l]=uu-ss[l]*60; acc[l]=b2[mm[l]]; }
    }

    for (int ch=0; ch<4; ch++){
        const int i0 = ch*64;
        __syncthreads();
        #pragma unroll
        for (int l=0;l<15;l++){
            int idx = tid + l*256;
            int m = idx >> 6, io = idx & 63;
            swc[io*60 + m] = w2[(size_t)m*256 + i0 + io];
        }
        __syncthreads();
        #pragma unroll
        for (int l=0;l<4;l++){
            int uu = tid + l*256;
            if (uu < 960){
                const float* yy = sy3 + ss[l]*256 + i0;
                float a = acc[l];
                #pragma unroll 8
                for (int io=0; io<64; io++) a += yy[io]*swc[io*60 + mm[l]];
                acc[l] = a;
            }
        }
    }
    __syncthreads();
    #pragma unroll
    for (int l=0;l<4;l++){
        int uu = tid + l*256;
        if (uu < 960){
            float a = acc[l];
            sy4[ss[l]*61 + mm[l]] = a>=0.f? a : 0.01f*a;
        }
    }
    __syncthreads();
    if (tid < 240){
        int s = tid/15, b = tid - s*15;
        const float* y4 = sy4 + s*61 + b*4;
        float ax=y4[0], ay=y4[1], az=y4[2], th=y4[3];
        float nr = sqrtf(ax*ax+ay*ay+az*az);
        float4 o;
        o.x = ax/nr; o.y = ay/nr; o.z = az/nr; o.w = th/81.0f;
        *(float4*)(at + (size_t)(n0+s)*60 + b*4) = o;
    }
}

// ---------------- K6: per-(n,t) Rodrigues + FK + ba_diff ----------------
__global__ __launch_bounds__(256)
void pose_kernel(const float* __restrict__ x5, const float* __restrict__ at,
                 float* __restrict__ out)
{
    const int gid = blockIdx.x*256 + threadIdx.x;
    if (gid >= NS*TL) return;
    const int n = gid / TL;
    const int t = gid - n*TL;
    const float ft = (float)t;

    float4 pv[12];
    {
        const float4* src = (const float4*)(x5 + (size_t)gid*48);
        #pragma unroll
        for (int i=0;i<12;i++) pv[i] = src[i];
    }
    float* p = (float*)pv;
    const float4* ab = (const float4*)(at + (size_t)n*60);

    float4 posv[12];
    float* pos = (float*)posv;
    pos[0]=p[0]; pos[1]=p[1]; pos[2]=p[2];
    float ba[15];

    const int PJ[15] = {0,1,2,0,4,5,0,7,8,9,8,11,12,8,14};
    const int CJ[15] = {1,2,3,4,5,6,7,8,9,10,11,12,13,14,15};

    #pragma unroll
    for (int b=0;b<15;b++){
        const int pj = PJ[b], cj = CJ[b];
        float bx = p[cj*3+0]-p[pj*3+0];
        float by = p[cj*3+1]-p[pj*3+1];
        float bz = p[cj*3+2]-p[pj*3+2];
        float bl = sqrtf(bx*bx+by*by+bz*bz);
        float ux = bx/bl, uy = by/bl, uz = bz/bl;
        float mx, my, mz;
        if (b==6 || b==7){
            mx=ux; my=uy; mz=uz;
        } else {
            float4 a = ab[b];
            float ang = a.w * ft;
            float cs, sn;
            __sincosf(ang, &sn, &cs);
            float kd = a.x*ux + a.y*uy + a.z*uz;
            float cx = a.y*uz - a.z*uy;
            float cy = a.z*ux - a.x*uz;
            float cz = a.x*uy - a.y*ux;
            float oc = (1.0f-cs)*kd;
            mx = ux*cs + cx*sn + a.x*oc;
            my = uy*cs + cy*sn + a.y*oc;
            mz = uz*cs + cz*sn + a.z*oc;
        }
        ba[b] = 1.0f - (mx*ux+my*uy+mz*uz);
        pos[cj*3+0] = pos[pj*3+0] + mx*bl;
        pos[cj*3+1] = pos[pj*3+1] + my*bl;
        pos[cj*3+2] = pos[pj*3+2] + mz*bl;
    }

    {
        float4* dst = (float4*)(out + (size_t)gid*48);
        #pragma unroll
        for (int i=0;i<12;i++) dst[i] = posv[i];
    }
    {
        float* bd = out + (size_t)NS*TL*48 + (size_t)gid*15;
        #pragma unroll
        for (int b=0;b<15;b++) bd[b] = ba[b];
    }
}

extern "C" void kernel_launch(void* const* d_in, const int* in_sizes, int n_in,
                              void* d_out, int out_size, void* d_ws, size_t ws_size,
                              hipStream_t stream)
{
    const float* x5    = (const float*)d_in[0];
    const float* noise = (const float*)d_in[1];
    const float* enc_w = (const float*)d_in[2];
    const float* enc_b = (const float*)d_in[3];
    const float* enc_g = (const float*)d_in[4];
    const float* enc_bb= (const float*)d_in[5];
    const float* ln_a  = (const float*)d_in[6];
    const float* ln_b  = (const float*)d_in[7];
    const float* wq = (const float*)d_in[8];
    const float* bq = (const float*)d_in[9];
    const float* wk = (const float*)d_in[10];
    const float* bk = (const float*)d_in[11];
    const float* wv = (const float*)d_in[12];
    const float* bv = (const float*)d_in[13];
    const float* wo = (const float*)d_in[14];
    const float* bo = (const float*)d_in[15];
    const float* w1 = (const float*)d_in[16];
    const float* b1 = (const float*)d_in[17];
    const float* g1 = (const float*)d_in[18];
    const float* bb1= (const float*)d_in[19];
    const float* w2 = (const float*)d_in[20];
    const float* b2 = (const float*)d_in[21];
    float* out = (float*)d_out;

    // ws: ctx (12.2 MB) + at (0.5 MB) = 12.7 MB (<= 14.7 MB known-safe)
    float* ws  = (float*)d_ws;
    float* ctx = ws;                                  // QROWS*48
    float* at  = ctx + (size_t)QROWS*48;              // NS*60

    // d_out scratch timeline: qkv (36.6 MB) -> dead -> y2 (12.2) + y3p (25.2) -> pose overwrites
    float* qkv = out;                                 // QROWS*144
    float* y2  = out;                                 // QROWS*48 (overwrites dead qkv)
    float* y3p = out + (size_t)QROWS*48;              // KSP*NS*DL

    qkv_kernel<<<496, 256, 0, stream>>>(x5, noise, enc_w, enc_b, enc_g, enc_bb,
                                        ln_a, ln_b, wq, bq, wk, bk, wv, bv, qkv);
    attn_kernel<<<512, 256, 0, stream>>>(qkv, ctx);
    proj_kernel<<<496, 256, 0, stream>>>(ctx, wo, bo, x5, noise,
                                         enc_w, enc_b, enc_g, enc_bb, y2);
    gemm1_kernel<<<32*KSP, 256, 0, stream>>>(y2, w1, y3p);
    head_kernel<<<128, 256, 0, stream>>>(y3p, w2, b2, b1, g1, bb1, at);
    pose_kernel<<<(NS*TL+255)/256, 256, 0, stream>>>(x5, at, out);

    (void)in_sizes; (void)n_in; (void)out_size; (void)ws_size;
}